// Round 1
// baseline (283.954 us; speedup 1.0000x reference)
//
#include <hip/hip_runtime.h>
#include <hip/hip_bf16.h>

typedef __attribute__((ext_vector_type(8))) short bf16x8;
typedef __attribute__((ext_vector_type(4))) float f32x4;

// ---------------------------------------------------------------------------
// h0: users -> emb[0] broadcast; items -> emb[x[i] - nu + 1]   (d = 128)
// ---------------------------------------------------------------------------
__global__ void build_h0_kernel(const int* __restrict__ x, const float* __restrict__ emb,
                                float* __restrict__ h0, int nu, int n) {
    int idx = blockIdx.x * blockDim.x + threadIdx.x;   // over n*32 float4
    int node = idx >> 5, c4 = idx & 31;
    if (node >= n) return;
    int row = (node < nu) ? 0 : (x[node] - nu + 1);
    reinterpret_cast<float4*>(h0)[node * 32 + c4] =
        reinterpret_cast<const float4*>(emb)[(size_t)row * 32 + c4];
}

// ---------------------------------------------------------------------------
// degree histogram over dst
// ---------------------------------------------------------------------------
__global__ void count_kernel(const int* __restrict__ dst, int* __restrict__ counts, int E) {
    int e = blockIdx.x * blockDim.x + threadIdx.x;
    if (e < E) atomicAdd(&counts[dst[e]], 1);
}

// ---------------------------------------------------------------------------
// single-block exclusive scan (n = 16384, 256 thr x 64 elems) + dinv = rsqrt(deg)
// deg includes the self loop (+1).
// ---------------------------------------------------------------------------
__global__ void scan_kernel(const int* __restrict__ counts, int* __restrict__ row_ptr,
                            float* __restrict__ dinv, int n) {
    __shared__ int sums[256];
    int t = threadIdx.x;
    int per = n >> 8;
    int base = t * per;
    int s = 0;
    for (int i = 0; i < per; ++i) s += counts[base + i];
    sums[t] = s;
    __syncthreads();
#pragma unroll
    for (int off = 1; off < 256; off <<= 1) {
        int v = (t >= off) ? sums[t - off] : 0;
        __syncthreads();
        sums[t] += v;
        __syncthreads();
    }
    int run = (t > 0) ? sums[t - 1] : 0;
    for (int i = 0; i < per; ++i) {
        int c = counts[base + i];
        row_ptr[base + i] = run;
        dinv[base + i] = rsqrtf((float)(c + 1));
        run += c;
    }
    if (t == 255) row_ptr[n] = run;
}

// ---------------------------------------------------------------------------
// scatter edges into CSR buckets (src sorted by dst)
// ---------------------------------------------------------------------------
__global__ void scatter_kernel(const int* __restrict__ src, const int* __restrict__ dst,
                               const int* __restrict__ row_ptr, int* __restrict__ wp,
                               int* __restrict__ srcs_sorted, int E) {
    int e = blockIdx.x * blockDim.x + threadIdx.x;
    if (e < E) {
        int d = dst[e];
        int p = atomicAdd(&wp[d], 1);
        srcs_sorted[row_ptr[d] + p] = src[e];
    }
}

// ---------------------------------------------------------------------------
// aggregation: out[v] = dinv[v] * ( sum_{e: s->v} dinv[s]*in[s] + dinv[v]*in[v] )
// C = 128 dims, one 128-thread block per node. Optional bias+relu epilogue.
// ---------------------------------------------------------------------------
__global__ __launch_bounds__(128) void agg128_kernel(
    const float* __restrict__ in, float* __restrict__ out,
    const int* __restrict__ row_ptr, const int* __restrict__ srcs,
    const float* __restrict__ dinv, const float* __restrict__ bias, int relu) {
    int v = blockIdx.x;
    int c = threadIdx.x;
    float dv = dinv[v];
    float acc = dv * in[(size_t)v * 128 + c];    // self loop (coef dv*dv after final scale)
    int s0 = row_ptr[v], s1 = row_ptr[v + 1];
    __shared__ int   s_src[128];
    __shared__ float s_w[128];
    for (int base = s0; base < s1; base += 128) {
        int m = min(128, s1 - base);
        __syncthreads();
        if (c < m) {
            int s = srcs[base + c];
            s_src[c] = s;
            s_w[c] = dinv[s];
        }
        __syncthreads();
        for (int j = 0; j < m; ++j)
            acc += s_w[j] * in[(size_t)s_src[j] * 128 + c];
    }
    acc *= dv;
    if (bias) acc += bias[c];
    if (relu) acc = fmaxf(acc, 0.f);
    out[(size_t)v * 128 + c] = acc;
}

// ---------------------------------------------------------------------------
// generic fp32 GEMM: C = act(A(MxK) @ B(KxN) + bias), 64x64 tile, BK=16,
// 256 threads, 4x4 per thread. OUT_BF16 selects output type.
// ---------------------------------------------------------------------------
template <bool OUT_BF16>
__global__ __launch_bounds__(256) void gemm_f32_kernel(
    const float* __restrict__ A, const float* __restrict__ B,
    const float* __restrict__ bias, void* __restrict__ Cout,
    int M, int N, int K, int act) {
    __shared__ float As[16][65];   // [k][m]
    __shared__ float Bs[16][65];   // [k][n]
    int t = threadIdx.x;
    int bm = blockIdx.x * 64, bn = blockIdx.y * 64;
    int tx = t & 15, ty = t >> 4;
    float acc[4][4] = {};
    for (int k0 = 0; k0 < K; k0 += 16) {
#pragma unroll
        for (int i = 0; i < 4; ++i) {      // A tile 64x16 -> As[k][m]
            int idx = t + i * 256;
            int m = idx >> 4, k = idx & 15;
            As[k][m] = A[(size_t)(bm + m) * K + k0 + k];
        }
#pragma unroll
        for (int i = 0; i < 4; ++i) {      // B tile 16x64 -> Bs[k][n]
            int idx = t + i * 256;
            int k = idx >> 6, nn = idx & 63;
            Bs[k][nn] = B[(size_t)(k0 + k) * N + bn + nn];
        }
        __syncthreads();
#pragma unroll
        for (int k = 0; k < 16; ++k) {
            float a[4], b[4];
#pragma unroll
            for (int i = 0; i < 4; ++i) a[i] = As[k][ty * 4 + i];
#pragma unroll
            for (int j = 0; j < 4; ++j) b[j] = Bs[k][tx * 4 + j];
#pragma unroll
            for (int i = 0; i < 4; ++i)
#pragma unroll
                for (int j = 0; j < 4; ++j) acc[i][j] = fmaf(a[i], b[j], acc[i][j]);
        }
        __syncthreads();
    }
#pragma unroll
    for (int i = 0; i < 4; ++i) {
#pragma unroll
        for (int j = 0; j < 4; ++j) {
            int row = bm + ty * 4 + i, col = bn + tx * 4 + j;
            float v = acc[i][j];
            if (bias) v += bias[col];
            if (act) v = fmaxf(v, 0.f);
            if (OUT_BF16)
                ((__hip_bfloat16*)Cout)[(size_t)row * N + col] = __float2bfloat16(v);
            else
                ((float*)Cout)[(size_t)row * N + col] = v;
        }
    }
}

// ---------------------------------------------------------------------------
// final: out[i][j] = clip(dot64(users[i], items[j]), 1, 5)  via bf16 MFMA.
// h3b is 16384x64 bf16; users rows [0,nu), items rows [nu,n).
// Block = 4 waves, each wave computes a 64x64 tile -> block tile 128x128.
// A frag (16x16x32): lane holds A[row=l&15][k=(l>>4)*8 + j] -> contiguous
// 16B load from row-major [node][64] storage; B identical by symmetry.
// C/D: col=lane&15, row=(lane>>4)*4+reg  [measured m89/m91].
// ---------------------------------------------------------------------------
__global__ __launch_bounds__(256) void final_gemm_kernel(
    const short* __restrict__ h3b, float* __restrict__ out, int nu, int ni) {
    int wid = threadIdx.x >> 6, lane = threadIdx.x & 63;
    int row0 = blockIdx.x * 128 + (wid >> 1) * 64;
    int col0 = blockIdx.y * 128 + (wid & 1) * 64;
    int lr = lane & 15;
    int kg = (lane >> 4) * 8;
    const short* Au = h3b;                       // users
    const short* Bi = h3b + (size_t)nu * 64;     // items
    bf16x8 a[4][2], b[4][2];
#pragma unroll
    for (int r = 0; r < 4; ++r)
#pragma unroll
        for (int kt = 0; kt < 2; ++kt) {
            a[r][kt] = *reinterpret_cast<const bf16x8*>(Au + (size_t)(row0 + r * 16 + lr) * 64 + kt * 32 + kg);
            b[r][kt] = *reinterpret_cast<const bf16x8*>(Bi + (size_t)(col0 + r * 16 + lr) * 64 + kt * 32 + kg);
        }
    f32x4 acc[4][4];
#pragma unroll
    for (int r = 0; r < 4; ++r)
#pragma unroll
        for (int c = 0; c < 4; ++c) {
            f32x4 z = {0.f, 0.f, 0.f, 0.f};
            z = __builtin_amdgcn_mfma_f32_16x16x32_bf16(a[r][0], b[c][0], z, 0, 0, 0);
            z = __builtin_amdgcn_mfma_f32_16x16x32_bf16(a[r][1], b[c][1], z, 0, 0, 0);
            acc[r][c] = z;
        }
    int rq = (lane >> 4) * 4;
#pragma unroll
    for (int r = 0; r < 4; ++r)
#pragma unroll
        for (int c = 0; c < 4; ++c)
#pragma unroll
            for (int q = 0; q < 4; ++q) {
                float v = acc[r][c][q];
                v = fminf(fmaxf(v, 1.f), 5.f);
                out[(size_t)(row0 + r * 16 + rq + q) * ni + col0 + c * 16 + lr] = v;
            }
}

// ---------------------------------------------------------------------------
extern "C" void kernel_launch(void* const* d_in, const int* in_sizes, int n_in,
                              void* d_out, int out_size, void* d_ws, size_t ws_size,
                              hipStream_t stream) {
    const int*   x   = (const int*)d_in[0];
    const int*   ei  = (const int*)d_in[1];
    const float* emb = (const float*)d_in[3];
    const float* W1  = (const float*)d_in[4];
    const float* b1  = (const float*)d_in[5];
    const float* W2  = (const float*)d_in[6];
    const float* b2  = (const float*)d_in[7];
    const float* Wl  = (const float*)d_in[8];
    const float* bl  = (const float*)d_in[9];
    float* out = (float*)d_out;

    const int n   = in_sizes[0];                 // 16384
    const int E   = in_sizes[1] / 2;             // 524288
    const int h1d = in_sizes[5];                 // 256
    const int d   = in_sizes[4] / h1d;           // 128
    const int embrows = in_sizes[3] / d;         // 8193
    const int nu  = n - (embrows - 1);           // 8192
    const int ni  = n - nu;                      // 8192

    const int* srcp = ei;
    const int* dstp = ei + E;

    char* w = (char*)d_ws;
    int*   counts  = (int*)(w + 0);              // 64 KB
    int*   row_ptr = (int*)(w + (64 << 10));     // 128 KB slot (n+1 ints)
    int*   wp      = (int*)(w + (192 << 10));    // 64 KB
    float* dinv    = (float*)(w + (256 << 10));  // 64 KB
    int*   srcs    = (int*)(w + (320 << 10));    // 2 MB
    float* h0      = (float*)(w + (4  << 20));   // 8 MB
    float* z1      = (float*)(w + (12 << 20));   // 8 MB
    float* h1      = (float*)(w + (20 << 20));   // 16 MB
    float* hw2     = h0;                         // reuse (h0 dead)
    float* h2      = z1;                         // reuse (z1 dead)
    __hip_bfloat16* h3b = (__hip_bfloat16*)(w + (20 << 20));  // reuse h1 (dead)

    hipMemsetAsync(counts, 0, (size_t)n * 4, stream);
    hipMemsetAsync(wp,     0, (size_t)n * 4, stream);

    // graph structure
    count_kernel<<<(E + 255) / 256, 256, 0, stream>>>(dstp, counts, E);
    scan_kernel<<<1, 256, 0, stream>>>(counts, row_ptr, dinv, n);
    scatter_kernel<<<(E + 255) / 256, 256, 0, stream>>>(srcp, dstp, row_ptr, wp, srcs, E);

    // h0
    build_h0_kernel<<<(n * 32 + 255) / 256, 256, 0, stream>>>(x, emb, h0, nu, n);

    // conv1: z1 = A·h0 ; h1 = relu(z1 @ W1 + b1)
    agg128_kernel<<<n, 128, 0, stream>>>(h0, z1, row_ptr, srcs, dinv, nullptr, 0);
    {
        dim3 g(16384 / 64, 256 / 64);
        gemm_f32_kernel<false><<<g, 256, 0, stream>>>(z1, W1, b1, h1, n, h1d, d, 1);
    }

    // conv2: hw2 = h1 @ W2 ; h2 = relu(A·hw2 + b2)
    {
        dim3 g(16384 / 64, 128 / 64);
        gemm_f32_kernel<false><<<g, 256, 0, stream>>>(h1, W2, nullptr, hw2, n, 128, h1d, 0);
    }
    agg128_kernel<<<n, 128, 0, stream>>>(hw2, h2, row_ptr, srcs, dinv, b2, 1);

    // h3 = relu(h2 @ Wl + bl) -> bf16
    {
        dim3 g(16384 / 64, 64 / 64);
        gemm_f32_kernel<true><<<g, 256, 0, stream>>>(h2, Wl, bl, (void*)h3b, n, 64, 128, 1);
    }

    // result = clip(users @ items.T, 1, 5)
    {
        dim3 g(nu / 128, ni / 128);
        final_gemm_kernel<<<g, 256, 0, stream>>>((const short*)h3b, out, nu, ni);
    }
}

// Round 3
// 263.152 us; speedup vs baseline: 1.0791x; 1.0791x over previous
//
#include <hip/hip_runtime.h>
#include <hip/hip_bf16.h>

typedef __attribute__((ext_vector_type(8))) short bf16x8;
typedef __attribute__((ext_vector_type(4))) float f32x4;

// ---------------------------------------------------------------------------
// zero two int arrays (replaces two rocclr fill dispatches)
// ---------------------------------------------------------------------------
__global__ void zero_kernel(int* __restrict__ a, int* __restrict__ b, int n) {
    int i = blockIdx.x * blockDim.x + threadIdx.x;
    if (i < n) { a[i] = 0; b[i] = 0; }
}

// ---------------------------------------------------------------------------
// h0: users -> emb[0] broadcast; items -> emb[x[i] - nu + 1]   (d = 128)
// ---------------------------------------------------------------------------
__global__ void build_h0_kernel(const int* __restrict__ x, const float* __restrict__ emb,
                                float* __restrict__ h0, int nu, int n) {
    int idx = blockIdx.x * blockDim.x + threadIdx.x;   // over n*32 float4
    int node = idx >> 5, c4 = idx & 31;
    if (node >= n) return;
    int row = (node < nu) ? 0 : (x[node] - nu + 1);
    reinterpret_cast<float4*>(h0)[node * 32 + c4] =
        reinterpret_cast<const float4*>(emb)[(size_t)row * 32 + c4];
}

// ---------------------------------------------------------------------------
// degree histogram over dst
// ---------------------------------------------------------------------------
__global__ void count_kernel(const int* __restrict__ dst, int* __restrict__ counts, int E) {
    int e = blockIdx.x * blockDim.x + threadIdx.x;
    if (e < E) atomicAdd(&counts[dst[e]], 1);
}

// ---------------------------------------------------------------------------
// single-block exclusive scan (n = 16384) + dinv = rsqrt(deg+1)
// ---------------------------------------------------------------------------
__global__ void scan_kernel(const int* __restrict__ counts, int* __restrict__ row_ptr,
                            float* __restrict__ dinv, int n) {
    __shared__ int sums[256];
    int t = threadIdx.x;
    int per = n >> 8;
    int base = t * per;
    int s = 0;
    for (int i = 0; i < per; ++i) s += counts[base + i];
    sums[t] = s;
    __syncthreads();
#pragma unroll
    for (int off = 1; off < 256; off <<= 1) {
        int v = (t >= off) ? sums[t - off] : 0;
        __syncthreads();
        sums[t] += v;
        __syncthreads();
    }
    int run = (t > 0) ? sums[t - 1] : 0;
    for (int i = 0; i < per; ++i) {
        int c = counts[base + i];
        row_ptr[base + i] = run;
        dinv[base + i] = rsqrtf((float)(c + 1));
        run += c;
    }
    if (t == 255) row_ptr[n] = run;
}

// ---------------------------------------------------------------------------
// scatter edges into CSR buckets (src sorted by dst)
// ---------------------------------------------------------------------------
__global__ void scatter_kernel(const int* __restrict__ src, const int* __restrict__ dst,
                               const int* __restrict__ row_ptr, int* __restrict__ wp,
                               int* __restrict__ srcs_sorted, int E) {
    int e = blockIdx.x * blockDim.x + threadIdx.x;
    if (e < E) {
        int d = dst[e];
        int p = atomicAdd(&wp[d], 1);
        srcs_sorted[row_ptr[d] + p] = src[e];
    }
}

// ---------------------------------------------------------------------------
// aggregation: out[v] = dinv[v] * ( sum_{e: s->v} dinv[s]*in[s] + dinv[v]*in[v] )
// C = 128 dims. One 128-thread block per node; lane = float4-column (32),
// subgroup (4) strides the edge list; LDS reduce at the end.
// ---------------------------------------------------------------------------
__global__ __launch_bounds__(128) void agg128_kernel(
    const float* __restrict__ in, float* __restrict__ out,
    const int* __restrict__ row_ptr, const int* __restrict__ srcs,
    const float* __restrict__ dinv, const float* __restrict__ bias, int relu) {
    int v = blockIdx.x;
    int t = threadIdx.x;
    int c4 = t & 31;      // which float4 of the 128-dim row
    int g  = t >> 5;      // edge subgroup 0..3
    const float4* in4 = reinterpret_cast<const float4*>(in);
    float4 acc = make_float4(0.f, 0.f, 0.f, 0.f);
    int s0 = row_ptr[v], s1 = row_ptr[v + 1];
    for (int e = s0 + g; e < s1; e += 4) {
        int s = srcs[e];
        float wgt = dinv[s];
        float4 xv = in4[(size_t)s * 32 + c4];
        acc.x = fmaf(wgt, xv.x, acc.x);
        acc.y = fmaf(wgt, xv.y, acc.y);
        acc.z = fmaf(wgt, xv.z, acc.z);
        acc.w = fmaf(wgt, xv.w, acc.w);
    }
    __shared__ float4 red[128];
    red[t] = acc;
    __syncthreads();
    if (g == 0) {
        float dv = dinv[v];
        float4 a0 = red[c4], a1 = red[32 + c4], a2 = red[64 + c4], a3 = red[96 + c4];
        float4 xv = in4[(size_t)v * 32 + c4];   // self loop
        float4 o;
        o.x = (a0.x + a1.x + a2.x + a3.x + dv * xv.x) * dv;
        o.y = (a0.y + a1.y + a2.y + a3.y + dv * xv.y) * dv;
        o.z = (a0.z + a1.z + a2.z + a3.z + dv * xv.z) * dv;
        o.w = (a0.w + a1.w + a2.w + a3.w + dv * xv.w) * dv;
        if (bias) {
            float4 b4 = reinterpret_cast<const float4*>(bias)[c4];
            o.x += b4.x; o.y += b4.y; o.z += b4.z; o.w += b4.w;
        }
        if (relu) {
            o.x = fmaxf(o.x, 0.f); o.y = fmaxf(o.y, 0.f);
            o.z = fmaxf(o.z, 0.f); o.w = fmaxf(o.w, 0.f);
        }
        reinterpret_cast<float4*>(out)[(size_t)v * 32 + c4] = o;
    }
}

// ---------------------------------------------------------------------------
// generic fp32 GEMM: C = act(A(MxK) @ B(KxN) + bias), 64x64 tile, BK=16,
// 256 threads, 4x4 per thread, float4 LDS fragments. OUT_BF16 selects output.
// Requires: M%64==0, N%64==0, K%16==0.
// ---------------------------------------------------------------------------
template <bool OUT_BF16>
__global__ __launch_bounds__(256) void gemm_f32_kernel(
    const float* __restrict__ A, const float* __restrict__ B,
    const float* __restrict__ bias, void* __restrict__ Cout,
    int M, int N, int K, int act) {
    __shared__ float As[16][68];   // [k][m], row = 272B (16B-aligned)
    __shared__ float Bs[16][68];   // [k][n]
    int t = threadIdx.x;
    int bm = blockIdx.x * 64, bn = blockIdx.y * 64;
    int tx = t & 15, ty = t >> 4;
    float acc[4][4] = {};
    for (int k0 = 0; k0 < K; k0 += 16) {
        {   // A tile 64x16: one float4 per thread, scatter to As[k][m]
            int m = t >> 2, k4 = (t & 3) * 4;
            float4 a = *reinterpret_cast<const float4*>(&A[(size_t)(bm + m) * K + k0 + k4]);
            As[k4 + 0][m] = a.x;
            As[k4 + 1][m] = a.y;
            As[k4 + 2][m] = a.z;
            As[k4 + 3][m] = a.w;
        }
        {   // B tile 16x64: one float4 per thread, contiguous in Bs[k][n]
            int k = t >> 4, n4 = (t & 15) * 4;
            float4 b = *reinterpret_cast<const float4*>(&B[(size_t)(k0 + k) * N + bn + n4]);
            *reinterpret_cast<float4*>(&Bs[k][n4]) = b;
        }
        __syncthreads();
#pragma unroll
        for (int k = 0; k < 16; ++k) {
            float4 a = *reinterpret_cast<const float4*>(&As[k][ty * 4]);   // broadcast
            float4 b = *reinterpret_cast<const float4*>(&Bs[k][tx * 4]);   // 2-way (free)
            float av[4] = {a.x, a.y, a.z, a.w};
            float bv[4] = {b.x, b.y, b.z, b.w};
#pragma unroll
            for (int i = 0; i < 4; ++i)
#pragma unroll
                for (int j = 0; j < 4; ++j) acc[i][j] = fmaf(av[i], bv[j], acc[i][j]);
        }
        __syncthreads();
    }
    int col = bn + tx * 4;
#pragma unroll
    for (int i = 0; i < 4; ++i) {
        int row = bm + ty * 4 + i;
        float v[4];
#pragma unroll
        for (int j = 0; j < 4; ++j) {
            v[j] = acc[i][j];
            if (bias) v[j] += bias[col + j];
            if (act) v[j] = fmaxf(v[j], 0.f);
        }
        if (OUT_BF16) {
            __hip_bfloat16 ob[4];
#pragma unroll
            for (int j = 0; j < 4; ++j) ob[j] = __float2bfloat16(v[j]);
            *reinterpret_cast<ushort4*>(&((__hip_bfloat16*)Cout)[(size_t)row * N + col]) =
                *reinterpret_cast<ushort4*>(ob);
        } else {
            *reinterpret_cast<float4*>(&((float*)Cout)[(size_t)row * N + col]) =
                make_float4(v[0], v[1], v[2], v[3]);
        }
    }
}

// ---------------------------------------------------------------------------
// final: out[i][j] = clip(dot64(users[i], items[j]), 1, 5)  via bf16 MFMA.
// Block = 4 waves; each wave does a 64x64 tile -> block tile 128x128.
// ---------------------------------------------------------------------------
__global__ __launch_bounds__(256) void final_gemm_kernel(
    const short* __restrict__ h3b, float* __restrict__ out, int nu, int ni) {
    int wid = threadIdx.x >> 6, lane = threadIdx.x & 63;
    int row0 = blockIdx.x * 128 + (wid >> 1) * 64;
    int col0 = blockIdx.y * 128 + (wid & 1) * 64;
    int lr = lane & 15;
    int kg = (lane >> 4) * 8;
    const short* Au = h3b;                       // users
    const short* Bi = h3b + (size_t)nu * 64;     // items
    bf16x8 a[4][2], b[4][2];
#pragma unroll
    for (int r = 0; r < 4; ++r)
#pragma unroll
        for (int kt = 0; kt < 2; ++kt) {
            a[r][kt] = *reinterpret_cast<const bf16x8*>(Au + (size_t)(row0 + r * 16 + lr) * 64 + kt * 32 + kg);
            b[r][kt] = *reinterpret_cast<const bf16x8*>(Bi + (size_t)(col0 + r * 16 + lr) * 64 + kt * 32 + kg);
        }
    f32x4 acc[4][4];
#pragma unroll
    for (int r = 0; r < 4; ++r)
#pragma unroll
        for (int c = 0; c < 4; ++c) {
            f32x4 z = {0.f, 0.f, 0.f, 0.f};
            z = __builtin_amdgcn_mfma_f32_16x16x32_bf16(a[r][0], b[c][0], z, 0, 0, 0);
            z = __builtin_amdgcn_mfma_f32_16x16x32_bf16(a[r][1], b[c][1], z, 0, 0, 0);
            acc[r][c] = z;
        }
    int rq = (lane >> 4) * 4;
#pragma unroll
    for (int r = 0; r < 4; ++r)
#pragma unroll
        for (int c = 0; c < 4; ++c)
#pragma unroll
            for (int q = 0; q < 4; ++q) {
                float v = acc[r][c][q];
                v = fminf(fmaxf(v, 1.f), 5.f);
                out[(size_t)(row0 + r * 16 + rq + q) * ni + col0 + c * 16 + lr] = v;
            }
}

// ---------------------------------------------------------------------------
extern "C" void kernel_launch(void* const* d_in, const int* in_sizes, int n_in,
                              void* d_out, int out_size, void* d_ws, size_t ws_size,
                              hipStream_t stream) {
    const int*   x   = (const int*)d_in[0];
    const int*   ei  = (const int*)d_in[1];
    const float* emb = (const float*)d_in[3];
    const float* W1  = (const float*)d_in[4];
    const float* b1  = (const float*)d_in[5];
    const float* W2  = (const float*)d_in[6];
    const float* b2  = (const float*)d_in[7];
    const float* Wl  = (const float*)d_in[8];
    const float* bl  = (const float*)d_in[9];
    float* out = (float*)d_out;

    const int n   = in_sizes[0];                 // 16384
    const int E   = in_sizes[1] / 2;             // 524288
    const int h1d = in_sizes[5];                 // 256
    const int d   = in_sizes[4] / h1d;           // 128
    const int embrows = in_sizes[3] / d;         // 8193
    const int nu  = n - (embrows - 1);           // 8192
    const int ni  = n - nu;                      // 8192

    const int* srcp = ei;
    const int* dstp = ei + E;

    char* w = (char*)d_ws;
    int*   counts  = (int*)(w + 0);              // 64 KB
    int*   row_ptr = (int*)(w + (64 << 10));     // 128 KB slot (n+1 ints)
    int*   wp      = (int*)(w + (192 << 10));    // 64 KB
    float* dinv    = (float*)(w + (256 << 10));  // 64 KB
    int*   srcs    = (int*)(w + (320 << 10));    // 2 MB
    float* h0      = (float*)(w + (4  << 20));   // 8 MB
    float* z1      = (float*)(w + (12 << 20));   // 8 MB
    float* h1      = (float*)(w + (20 << 20));   // 16 MB
    float* hw2     = h0;                         // reuse (h0 dead)
    float* h2      = z1;                         // reuse (z1 dead)
    __hip_bfloat16* h3b = (__hip_bfloat16*)(w + (20 << 20));  // reuse h1 (dead)

    // zero the two atomic-counter arrays (one dispatch, not two rocclr fills)
    zero_kernel<<<(n + 255) / 256, 256, 0, stream>>>(counts, wp, n);

    // graph structure
    count_kernel<<<(E + 255) / 256, 256, 0, stream>>>(dstp, counts, E);
    scan_kernel<<<1, 256, 0, stream>>>(counts, row_ptr, dinv, n);
    scatter_kernel<<<(E + 255) / 256, 256, 0, stream>>>(srcp, dstp, row_ptr, wp, srcs, E);

    // h0
    build_h0_kernel<<<(n * 32 + 255) / 256, 256, 0, stream>>>(x, emb, h0, nu, n);

    // conv1: z1 = A·h0 ; h1 = relu(z1 @ W1 + b1)
    agg128_kernel<<<n, 128, 0, stream>>>(h0, z1, row_ptr, srcs, dinv, nullptr, 0);
    {
        dim3 g(16384 / 64, 256 / 64);
        gemm_f32_kernel<false><<<g, 256, 0, stream>>>(z1, W1, b1, h1, n, h1d, d, 1);
    }

    // conv2: hw2 = h1 @ W2 ; h2 = relu(A·hw2 + b2)
    {
        dim3 g(16384 / 64, 128 / 64);
        gemm_f32_kernel<false><<<g, 256, 0, stream>>>(h1, W2, nullptr, hw2, n, 128, h1d, 0);
    }
    agg128_kernel<<<n, 128, 0, stream>>>(hw2, h2, row_ptr, srcs, dinv, b2, 1);

    // h3 = relu(h2 @ Wl + bl) -> bf16
    {
        dim3 g(16384 / 64, 64 / 64);
        gemm_f32_kernel<true><<<g, 256, 0, stream>>>(h2, Wl, bl, (void*)h3b, n, 64, 128, 1);
    }

    // result = clip(users @ items.T, 1, 5)
    {
        dim3 g(nu / 128, ni / 128);
        final_gemm_kernel<<<g, 256, 0, stream>>>((const short*)h3b, out, nu, ni);
    }
}

// Round 4
// 216.325 us; speedup vs baseline: 1.3126x; 1.2165x over previous
//
#include <hip/hip_runtime.h>
#include <hip/hip_bf16.h>

typedef __attribute__((ext_vector_type(8))) short bf16x8;
typedef __attribute__((ext_vector_type(4))) float f32x4;

static __device__ __forceinline__ float bflo(unsigned int w) {
    union { unsigned int i; float f; } u; u.i = w << 16; return u.f;
}
static __device__ __forceinline__ float bfhi(unsigned int w) {
    union { unsigned int i; float f; } u; u.i = w & 0xffff0000u; return u.f;
}
static __device__ __forceinline__ unsigned short f2bf(float f) {
    __hip_bfloat16 h = __float2bfloat16(f);
    union { __hip_bfloat16 b; unsigned short s; } u; u.b = h; return u.s;
}

// ---------------------------------------------------------------------------
// zero two int arrays
// ---------------------------------------------------------------------------
__global__ void zero_kernel(int* __restrict__ a, int* __restrict__ b, int n) {
    int i = blockIdx.x * blockDim.x + threadIdx.x;
    if (i < n) { a[i] = 0; b[i] = 0; }
}

// ---------------------------------------------------------------------------
// degree histogram over dst
// ---------------------------------------------------------------------------
__global__ void count_kernel(const int* __restrict__ dst, int* __restrict__ counts, int E) {
    int e = blockIdx.x * blockDim.x + threadIdx.x;
    if (e < E) atomicAdd(&counts[dst[e]], 1);
}

// ---------------------------------------------------------------------------
// single-block exclusive scan (n = 16384) + dinv = rsqrt(deg+1)
// ---------------------------------------------------------------------------
__global__ void scan_kernel(const int* __restrict__ counts, int* __restrict__ row_ptr,
                            float* __restrict__ dinv, int n) {
    __shared__ int sums[256];
    int t = threadIdx.x;
    int per = n >> 8;
    int base = t * per;
    int s = 0;
    for (int i = 0; i < per; ++i) s += counts[base + i];
    sums[t] = s;
    __syncthreads();
#pragma unroll
    for (int off = 1; off < 256; off <<= 1) {
        int v = (t >= off) ? sums[t - off] : 0;
        __syncthreads();
        sums[t] += v;
        __syncthreads();
    }
    int run = (t > 0) ? sums[t - 1] : 0;
    for (int i = 0; i < per; ++i) {
        int c = counts[base + i];
        row_ptr[base + i] = run;
        dinv[base + i] = rsqrtf((float)(c + 1));
        run += c;
    }
    if (t == 255) row_ptr[n] = run;
}

// ---------------------------------------------------------------------------
// scatter edges into CSR buckets (src sorted by dst)
// ---------------------------------------------------------------------------
__global__ void scatter_kernel(const int* __restrict__ src, const int* __restrict__ dst,
                               const int* __restrict__ row_ptr, int* __restrict__ wp,
                               int* __restrict__ srcs_sorted, int E) {
    int e = blockIdx.x * blockDim.x + threadIdx.x;
    if (e < E) {
        int d = dst[e];
        int p = atomicAdd(&wp[d], 1);
        srcs_sorted[row_ptr[d] + p] = src[e];
    }
}

// ---------------------------------------------------------------------------
// weight prep: transpose + convert to bf16.
// W1 128x256 -> W1t 256x128 ; W2 256x128 -> W2t 128x256 ; Wl 128x64 -> Wlt 64x128
// ---------------------------------------------------------------------------
__global__ void prep_weights_kernel(const float* __restrict__ W1, const float* __restrict__ W2,
                                    const float* __restrict__ Wl,
                                    unsigned short* __restrict__ W1t,
                                    unsigned short* __restrict__ W2t,
                                    unsigned short* __restrict__ Wlt) {
    int i = blockIdx.x * blockDim.x + threadIdx.x;
    if (i < 32768) {                       // W1t[n][k], n in [0,256), k in [0,128)
        int nn = i >> 7, kk = i & 127;
        W1t[i] = f2bf(W1[kk * 256 + nn]);
    } else if (i < 65536) {                // W2t[n][k], n in [0,128), k in [0,256)
        int j = i - 32768;
        int nn = j >> 8, kk = j & 255;
        W2t[j] = f2bf(W2[kk * 128 + nn]);
    } else if (i < 73728) {                // Wlt[n][k], n in [0,64), k in [0,128)
        int j = i - 65536;
        int nn = j >> 7, kk = j & 127;
        Wlt[j] = f2bf(Wl[kk * 64 + nn]);
    }
}

// ---------------------------------------------------------------------------
// h0 (bf16): users -> emb[0]; items -> emb[x[i]-nu+1]; d=128
// ---------------------------------------------------------------------------
__global__ void build_h0b_kernel(const int* __restrict__ x, const float* __restrict__ emb,
                                 unsigned short* __restrict__ h0, int nu, int n) {
    int idx = blockIdx.x * blockDim.x + threadIdx.x;   // over n*16 (8 dims each)
    int node = idx >> 4, c8 = idx & 15;
    if (node >= n) return;
    int row = (node < nu) ? 0 : (x[node] - nu + 1);
    float4 f0 = reinterpret_cast<const float4*>(emb)[(size_t)row * 32 + c8 * 2];
    float4 f1 = reinterpret_cast<const float4*>(emb)[(size_t)row * 32 + c8 * 2 + 1];
    union { unsigned short s[8]; uint4 v; } o;
    o.s[0] = f2bf(f0.x); o.s[1] = f2bf(f0.y); o.s[2] = f2bf(f0.z); o.s[3] = f2bf(f0.w);
    o.s[4] = f2bf(f1.x); o.s[5] = f2bf(f1.y); o.s[6] = f2bf(f1.z); o.s[7] = f2bf(f1.w);
    *reinterpret_cast<uint4*>(h0 + (size_t)node * 128 + c8 * 8) = o.v;
}

// ---------------------------------------------------------------------------
// aggregation over bf16 rows (fp32 accumulate):
// out[v] = bf16( dinv[v]*(sum_e dinv[s]*in[s] + dinv[v]*in[v]) + bias ), relu opt.
// 128 thr/block, 1 node/block. 16-lane groups own a 16B (8-dim) row segment;
// 8 subgroups stride the edge list. LDS reduce with x9 pad (conflict-free).
// ---------------------------------------------------------------------------
__global__ __launch_bounds__(128) void agg_bf16_kernel(
    const unsigned short* __restrict__ in, unsigned short* __restrict__ out,
    const int* __restrict__ row_ptr, const int* __restrict__ srcs,
    const float* __restrict__ dinv, const float* __restrict__ bias, int relu) {
    int v = blockIdx.x;
    int t = threadIdx.x;
    int l16 = t & 15;      // which 8-dim segment
    int g   = t >> 4;      // edge subgroup 0..7
    float acc[8] = {0.f, 0.f, 0.f, 0.f, 0.f, 0.f, 0.f, 0.f};
    int s0 = row_ptr[v], s1 = row_ptr[v + 1];
    for (int e = s0 + g; e < s1; e += 8) {
        int s = srcs[e];
        float wgt = dinv[s];
        uint4 p = *reinterpret_cast<const uint4*>(in + (size_t)s * 128 + l16 * 8);
        acc[0] = fmaf(wgt, bflo(p.x), acc[0]);
        acc[1] = fmaf(wgt, bfhi(p.x), acc[1]);
        acc[2] = fmaf(wgt, bflo(p.y), acc[2]);
        acc[3] = fmaf(wgt, bfhi(p.y), acc[3]);
        acc[4] = fmaf(wgt, bflo(p.z), acc[4]);
        acc[5] = fmaf(wgt, bfhi(p.z), acc[5]);
        acc[6] = fmaf(wgt, bflo(p.w), acc[6]);
        acc[7] = fmaf(wgt, bfhi(p.w), acc[7]);
    }
    __shared__ float red[8 * 144];         // [g][l16*9 + d]
#pragma unroll
    for (int d = 0; d < 8; ++d) red[g * 144 + l16 * 9 + d] = acc[d];
    __syncthreads();
    // thread t owns dim t
    int seg = t >> 3, d = t & 7;
    float sum = 0.f;
#pragma unroll
    for (int gg = 0; gg < 8; ++gg) sum += red[gg * 144 + seg * 9 + d];
    float dv = dinv[v];
    float self = bflo((unsigned int)in[(size_t)v * 128 + t]);
    float o = (sum + dv * self) * dv;
    if (bias) o += bias[t];
    if (relu) o = fmaxf(o, 0.f);
    out[(size_t)v * 128 + t] = f2bf(o);
}

// ---------------------------------------------------------------------------
// MFMA GEMM: C(MxN, bf16) = act(A(MxK, bf16) @ Bt(NxK, bf16)^T + bias)
// grid (M/64, N/64), 256 thr = 4 waves; wave w handles rows [bm+16w, +16).
// A-frag and B-frag are both contiguous 16B loads (Bt pre-transposed).
// ---------------------------------------------------------------------------
__global__ __launch_bounds__(256) void mfma_gemm_kernel(
    const unsigned short* __restrict__ A, const unsigned short* __restrict__ Bt,
    const float* __restrict__ bias, unsigned short* __restrict__ C,
    int M, int N, int K, int relu) {
    int w = threadIdx.x >> 6, lane = threadIdx.x & 63;
    int r0 = blockIdx.x * 64 + w * 16;
    int bn = blockIdx.y * 64;
    int lr = lane & 15, kg = (lane >> 4) * 8;
    f32x4 acc[4] = {{0,0,0,0},{0,0,0,0},{0,0,0,0},{0,0,0,0}};
    for (int k0 = 0; k0 < K; k0 += 32) {
        bf16x8 a = *reinterpret_cast<const bf16x8*>(A + (size_t)(r0 + lr) * K + k0 + kg);
#pragma unroll
        for (int c = 0; c < 4; ++c) {
            bf16x8 b = *reinterpret_cast<const bf16x8*>(Bt + (size_t)(bn + c * 16 + lr) * K + k0 + kg);
            acc[c] = __builtin_amdgcn_mfma_f32_16x16x32_bf16(a, b, acc[c], 0, 0, 0);
        }
    }
    int rq = (lane >> 4) * 4;
#pragma unroll
    for (int c = 0; c < 4; ++c) {
        int col = bn + c * 16 + lr;
        float bs = bias ? bias[col] : 0.f;
#pragma unroll
        for (int q = 0; q < 4; ++q) {
            float vv = acc[c][q] + bs;
            if (relu) vv = fmaxf(vv, 0.f);
            C[(size_t)(r0 + rq + q) * N + col] = f2bf(vv);
        }
    }
}

// ---------------------------------------------------------------------------
// final: out[i][j] = clip(dot64(users[i], items[j]), 1, 5)  via bf16 MFMA.
// Block = 4 waves; each wave does a 64x64 tile -> block tile 128x128.
// ---------------------------------------------------------------------------
__global__ __launch_bounds__(256) void final_gemm_kernel(
    const short* __restrict__ h3b, float* __restrict__ out, int nu, int ni) {
    int wid = threadIdx.x >> 6, lane = threadIdx.x & 63;
    int row0 = blockIdx.x * 128 + (wid >> 1) * 64;
    int col0 = blockIdx.y * 128 + (wid & 1) * 64;
    int lr = lane & 15;
    int kg = (lane >> 4) * 8;
    const short* Au = h3b;                       // users
    const short* Bi = h3b + (size_t)nu * 64;     // items
    bf16x8 a[4][2], b[4][2];
#pragma unroll
    for (int r = 0; r < 4; ++r)
#pragma unroll
        for (int kt = 0; kt < 2; ++kt) {
            a[r][kt] = *reinterpret_cast<const bf16x8*>(Au + (size_t)(row0 + r * 16 + lr) * 64 + kt * 32 + kg);
            b[r][kt] = *reinterpret_cast<const bf16x8*>(Bi + (size_t)(col0 + r * 16 + lr) * 64 + kt * 32 + kg);
        }
    f32x4 acc[4][4];
#pragma unroll
    for (int r = 0; r < 4; ++r)
#pragma unroll
        for (int c = 0; c < 4; ++c) {
            f32x4 z = {0.f, 0.f, 0.f, 0.f};
            z = __builtin_amdgcn_mfma_f32_16x16x32_bf16(a[r][0], b[c][0], z, 0, 0, 0);
            z = __builtin_amdgcn_mfma_f32_16x16x32_bf16(a[r][1], b[c][1], z, 0, 0, 0);
            acc[r][c] = z;
        }
    int rq = (lane >> 4) * 4;
#pragma unroll
    for (int r = 0; r < 4; ++r)
#pragma unroll
        for (int c = 0; c < 4; ++c)
#pragma unroll
            for (int q = 0; q < 4; ++q) {
                float v = acc[r][c][q];
                v = fminf(fmaxf(v, 1.f), 5.f);
                out[(size_t)(row0 + r * 16 + rq + q) * ni + col0 + c * 16 + lr] = v;
            }
}

// ---------------------------------------------------------------------------
extern "C" void kernel_launch(void* const* d_in, const int* in_sizes, int n_in,
                              void* d_out, int out_size, void* d_ws, size_t ws_size,
                              hipStream_t stream) {
    const int*   x   = (const int*)d_in[0];
    const int*   ei  = (const int*)d_in[1];
    const float* emb = (const float*)d_in[3];
    const float* W1  = (const float*)d_in[4];
    const float* b1  = (const float*)d_in[5];
    const float* W2  = (const float*)d_in[6];
    const float* b2  = (const float*)d_in[7];
    const float* Wl  = (const float*)d_in[8];
    const float* bl  = (const float*)d_in[9];
    float* out = (float*)d_out;

    const int n   = in_sizes[0];                 // 16384
    const int E   = in_sizes[1] / 2;             // 524288
    const int h1d = in_sizes[5];                 // 256
    const int d   = in_sizes[4] / h1d;           // 128
    const int embrows = in_sizes[3] / d;         // 8193
    const int nu  = n - (embrows - 1);           // 8192
    const int ni  = n - nu;                      // 8192

    const int* srcp = ei;
    const int* dstp = ei + E;

    char* w = (char*)d_ws;
    int*   counts  = (int*)(w + 0);                       // 64 KB
    int*   row_ptr = (int*)(w + (64 << 10));              // n+1 ints
    int*   wp      = (int*)(w + (192 << 10));             // 64 KB
    float* dinv    = (float*)(w + (256 << 10));           // 64 KB
    int*   srcs    = (int*)(w + (320 << 10));             // 2 MB
    unsigned short* W1t = (unsigned short*)(w + 2621440);   // 64 KB
    unsigned short* W2t = (unsigned short*)(w + 2686976);   // 64 KB
    unsigned short* Wlt = (unsigned short*)(w + 2752512);   // 16 KB
    unsigned short* h0b  = (unsigned short*)(w + (4  << 20));  // 4 MB
    unsigned short* z1b  = (unsigned short*)(w + (8  << 20));  // 4 MB
    unsigned short* h1b  = (unsigned short*)(w + (12 << 20));  // 8 MB
    unsigned short* hw2b = (unsigned short*)(w + (20 << 20));  // 4 MB
    unsigned short* h2b  = (unsigned short*)(w + (24 << 20));  // 4 MB
    unsigned short* h3b  = (unsigned short*)(w + (28 << 20));  // 2 MB

    // zero atomic counters
    zero_kernel<<<(n + 255) / 256, 256, 0, stream>>>(counts, wp, n);

    // graph structure
    count_kernel<<<(E + 255) / 256, 256, 0, stream>>>(dstp, counts, E);
    scan_kernel<<<1, 256, 0, stream>>>(counts, row_ptr, dinv, n);
    scatter_kernel<<<(E + 255) / 256, 256, 0, stream>>>(srcp, dstp, row_ptr, wp, srcs, E);

    // weights -> transposed bf16 ; h0 -> bf16
    prep_weights_kernel<<<288, 256, 0, stream>>>(W1, W2, Wl, W1t, W2t, Wlt);
    build_h0b_kernel<<<(n * 16 + 255) / 256, 256, 0, stream>>>(x, emb, h0b, nu, n);

    // conv1: z1 = A·h0 ; h1 = relu(z1 @ W1 + b1)
    agg_bf16_kernel<<<n, 128, 0, stream>>>(h0b, z1b, row_ptr, srcs, dinv, nullptr, 0);
    {
        dim3 g(n / 64, h1d / 64);
        mfma_gemm_kernel<<<g, 256, 0, stream>>>(z1b, W1t, b1, h1b, n, h1d, d, 1);
    }

    // conv2: hw2 = h1 @ W2 ; h2 = relu(A·hw2 + b2)
    {
        dim3 g(n / 64, 128 / 64);
        mfma_gemm_kernel<<<g, 256, 0, stream>>>(h1b, W2t, nullptr, hw2b, n, 128, h1d, 0);
    }
    agg_bf16_kernel<<<n, 128, 0, stream>>>(hw2b, h2b, row_ptr, srcs, dinv, b2, 1);

    // h3 = relu(h2 @ Wl + bl)
    {
        dim3 g(n / 64, 64 / 64);
        mfma_gemm_kernel<<<g, 256, 0, stream>>>(h2b, Wlt, bl, h3b, n, 64, 128, 1);
    }

    // result = clip(users @ items.T, 1, 5)
    {
        dim3 g(nu / 128, ni / 128);
        final_gemm_kernel<<<g, 256, 0, stream>>>((const short*)h3b, out, nu, ni);
    }
}

// Round 5
// 199.227 us; speedup vs baseline: 1.4253x; 1.0858x over previous
//
#include <hip/hip_runtime.h>
#include <hip/hip_bf16.h>

typedef __attribute__((ext_vector_type(8))) short bf16x8;
typedef __attribute__((ext_vector_type(4))) float f32x4;

static __device__ __forceinline__ float bflo(unsigned int w) {
    union { unsigned int i; float f; } u; u.i = w << 16; return u.f;
}
static __device__ __forceinline__ float bfhi(unsigned int w) {
    union { unsigned int i; float f; } u; u.i = w & 0xffff0000u; return u.f;
}
static __device__ __forceinline__ unsigned short f2bf(float f) {
    __hip_bfloat16 h = __float2bfloat16(f);
    union { __hip_bfloat16 b; unsigned short s; } u; u.b = h; return u.s;
}

// ---------------------------------------------------------------------------
// zero two int arrays
// ---------------------------------------------------------------------------
__global__ void zero_kernel(int* __restrict__ a, int* __restrict__ b, int n) {
    int i = blockIdx.x * blockDim.x + threadIdx.x;
    if (i < n) { a[i] = 0; b[i] = 0; }
}

// ---------------------------------------------------------------------------
// degree histogram over dst
// ---------------------------------------------------------------------------
__global__ void count_kernel(const int* __restrict__ dst, int* __restrict__ counts, int E) {
    int e = blockIdx.x * blockDim.x + threadIdx.x;
    if (e < E) atomicAdd(&counts[dst[e]], 1);
}

// ---------------------------------------------------------------------------
// single-block scan, COALESCED column-major bucket order.
// Thread t owns column {v = i*256 + t}; bucket offsets assigned column-major.
// Consumers use row_ptr[v] + counts[v] as the bucket end (order-free).
// Also emits dinv = rsqrt(count+1).
// ---------------------------------------------------------------------------
__global__ __launch_bounds__(256) void scan_kernel(const int* __restrict__ counts,
                                                   int* __restrict__ row_ptr,
                                                   float* __restrict__ dinv, int n) {
    int t = threadIdx.x;
    int rows = n >> 8;                 // 64
    int s = 0;
    for (int i = 0; i < rows; ++i) s += counts[i * 256 + t];   // coalesced
    __shared__ int sums[256];
    sums[t] = s;
    __syncthreads();
#pragma unroll
    for (int off = 1; off < 256; off <<= 1) {
        int v = (t >= off) ? sums[t - off] : 0;
        __syncthreads();
        sums[t] += v;
        __syncthreads();
    }
    int run = (t > 0) ? sums[t - 1] : 0;
    for (int i = 0; i < rows; ++i) {
        int v = i * 256 + t;
        int c = counts[v];
        row_ptr[v] = run;              // coalesced
        dinv[v] = rsqrtf((float)(c + 1));
        run += c;
    }
}

// ---------------------------------------------------------------------------
// scatter edges into CSR buckets (src grouped by dst; intra-bucket order free)
// ---------------------------------------------------------------------------
__global__ void scatter_kernel(const int* __restrict__ src, const int* __restrict__ dst,
                               const int* __restrict__ row_ptr, int* __restrict__ wp,
                               int* __restrict__ srcs_sorted, int E) {
    int e = blockIdx.x * blockDim.x + threadIdx.x;
    if (e < E) {
        int d = dst[e];
        int p = atomicAdd(&wp[d], 1);
        srcs_sorted[row_ptr[d] + p] = src[e];
    }
}

// ---------------------------------------------------------------------------
// merged prep: h0 (bf16) + transposed bf16 weights, one dispatch.
// threads [0, n*16)           : h0 rows (8 dims per thread)
// threads [n*16, n*16+73728)  : W1t (32768) | W2t (32768) | Wlt (8192)
// ---------------------------------------------------------------------------
__global__ void prep_kernel(const int* __restrict__ x, const float* __restrict__ emb,
                            const float* __restrict__ W1, const float* __restrict__ W2,
                            const float* __restrict__ Wl,
                            unsigned short* __restrict__ h0,
                            unsigned short* __restrict__ W1t,
                            unsigned short* __restrict__ W2t,
                            unsigned short* __restrict__ Wlt,
                            int nu, int n) {
    int i = blockIdx.x * blockDim.x + threadIdx.x;
    int H = n * 16;
    if (i < H) {
        int node = i >> 4, c8 = i & 15;
        int row = (node < nu) ? 0 : (x[node] - nu + 1);
        float4 f0 = reinterpret_cast<const float4*>(emb)[(size_t)row * 32 + c8 * 2];
        float4 f1 = reinterpret_cast<const float4*>(emb)[(size_t)row * 32 + c8 * 2 + 1];
        union { unsigned short s[8]; uint4 v; } o;
        o.s[0] = f2bf(f0.x); o.s[1] = f2bf(f0.y); o.s[2] = f2bf(f0.z); o.s[3] = f2bf(f0.w);
        o.s[4] = f2bf(f1.x); o.s[5] = f2bf(f1.y); o.s[6] = f2bf(f1.z); o.s[7] = f2bf(f1.w);
        *reinterpret_cast<uint4*>(h0 + (size_t)node * 128 + c8 * 8) = o.v;
        return;
    }
    int j = i - H;
    if (j < 32768) {                       // W1t[nn][kk] = W1[kk][nn], 256x128
        int nn = j >> 7, kk = j & 127;
        W1t[j] = f2bf(W1[kk * 256 + nn]);
    } else if (j < 65536) {                // W2t[nn][kk] = W2[kk][nn], 128x256
        int jj = j - 32768;
        int nn = jj >> 8, kk = jj & 255;
        W2t[jj] = f2bf(W2[kk * 128 + nn]);
    } else if (j < 73728) {                // Wlt[nn][kk] = Wl[kk][nn], 64x128
        int jj = j - 65536;
        int nn = jj >> 7, kk = jj & 127;
        Wlt[jj] = f2bf(Wl[kk * 64 + nn]);
    }
}

// ---------------------------------------------------------------------------
// aggregation (bf16 in/out, fp32 accumulate), ONE WAVE per node.
// lane&15 -> 8-dim segment; lane>>4 -> edge subgroup (4); shfl-xor reduce.
// out[v] = bf16( dinv[v]*(sum_e dinv[s]*in[s] + dinv[v]*in[v]) + bias ), relu opt.
// ---------------------------------------------------------------------------
__global__ __launch_bounds__(64) void agg_bf16_kernel(
    const unsigned short* __restrict__ in, unsigned short* __restrict__ out,
    const int* __restrict__ row_ptr, const int* __restrict__ cnt,
    const int* __restrict__ srcs, const float* __restrict__ dinv,
    const float* __restrict__ bias, int relu) {
    int v = blockIdx.x;
    int lane = threadIdx.x;
    int l16 = lane & 15;
    int g = lane >> 4;
    float acc[8] = {0.f, 0.f, 0.f, 0.f, 0.f, 0.f, 0.f, 0.f};
    int s0 = row_ptr[v];
    int s1 = s0 + cnt[v];
    for (int e = s0 + g; e < s1; e += 4) {
        int s = srcs[e];
        float wgt = dinv[s];
        uint4 p = *reinterpret_cast<const uint4*>(in + (size_t)s * 128 + l16 * 8);
        acc[0] = fmaf(wgt, bflo(p.x), acc[0]);
        acc[1] = fmaf(wgt, bfhi(p.x), acc[1]);
        acc[2] = fmaf(wgt, bflo(p.y), acc[2]);
        acc[3] = fmaf(wgt, bfhi(p.y), acc[3]);
        acc[4] = fmaf(wgt, bflo(p.z), acc[4]);
        acc[5] = fmaf(wgt, bfhi(p.z), acc[5]);
        acc[6] = fmaf(wgt, bflo(p.w), acc[6]);
        acc[7] = fmaf(wgt, bfhi(p.w), acc[7]);
    }
#pragma unroll
    for (int d = 0; d < 8; ++d) {
        acc[d] += __shfl_xor(acc[d], 16, 64);
        acc[d] += __shfl_xor(acc[d], 32, 64);
    }
    if (g == 0) {
        float dv = dinv[v];
        uint4 sp = *reinterpret_cast<const uint4*>(in + (size_t)v * 128 + l16 * 8);
        float self[8] = {bflo(sp.x), bfhi(sp.x), bflo(sp.y), bfhi(sp.y),
                         bflo(sp.z), bfhi(sp.z), bflo(sp.w), bfhi(sp.w)};
        union { unsigned short s[8]; uint4 u; } o;
#pragma unroll
        for (int d = 0; d < 8; ++d) {
            float val = (acc[d] + dv * self[d]) * dv;
            if (bias) val += bias[l16 * 8 + d];
            if (relu) val = fmaxf(val, 0.f);
            o.s[d] = f2bf(val);
        }
        *reinterpret_cast<uint4*>(out + (size_t)v * 128 + l16 * 8) = o.u;
    }
}

// ---------------------------------------------------------------------------
// MFMA GEMM: C(MxN, bf16) = act(A(MxK, bf16) @ Bt(NxK, bf16)^T + bias)
// grid (M/64, N/64), 256 thr = 4 waves; wave w handles rows [bm+16w, +16).
// ---------------------------------------------------------------------------
__global__ __launch_bounds__(256) void mfma_gemm_kernel(
    const unsigned short* __restrict__ A, const unsigned short* __restrict__ Bt,
    const float* __restrict__ bias, unsigned short* __restrict__ C,
    int M, int N, int K, int relu) {
    int w = threadIdx.x >> 6, lane = threadIdx.x & 63;
    int r0 = blockIdx.x * 64 + w * 16;
    int bn = blockIdx.y * 64;
    int lr = lane & 15, kg = (lane >> 4) * 8;
    f32x4 acc[4] = {{0,0,0,0},{0,0,0,0},{0,0,0,0},{0,0,0,0}};
    for (int k0 = 0; k0 < K; k0 += 32) {
        bf16x8 a = *reinterpret_cast<const bf16x8*>(A + (size_t)(r0 + lr) * K + k0 + kg);
#pragma unroll
        for (int c = 0; c < 4; ++c) {
            bf16x8 b = *reinterpret_cast<const bf16x8*>(Bt + (size_t)(bn + c * 16 + lr) * K + k0 + kg);
            acc[c] = __builtin_amdgcn_mfma_f32_16x16x32_bf16(a, b, acc[c], 0, 0, 0);
        }
    }
    int rq = (lane >> 4) * 4;
#pragma unroll
    for (int c = 0; c < 4; ++c) {
        int col = bn + c * 16 + lr;
        float bs = bias ? bias[col] : 0.f;
#pragma unroll
        for (int q = 0; q < 4; ++q) {
            float vv = acc[c][q] + bs;
            if (relu) vv = fmaxf(vv, 0.f);
            C[(size_t)(r0 + rq + q) * N + col] = f2bf(vv);
        }
    }
}

// ---------------------------------------------------------------------------
// final: out[i][j] = clip(dot64(users[i], items[j]), 1, 5)  via bf16 MFMA.
// Block = 4 waves; each wave does a 64x64 tile -> block tile 128x128.
// ---------------------------------------------------------------------------
__global__ __launch_bounds__(256) void final_gemm_kernel(
    const short* __restrict__ h3b, float* __restrict__ out, int nu, int ni) {
    int wid = threadIdx.x >> 6, lane = threadIdx.x & 63;
    int row0 = blockIdx.x * 128 + (wid >> 1) * 64;
    int col0 = blockIdx.y * 128 + (wid & 1) * 64;
    int lr = lane & 15;
    int kg = (lane >> 4) * 8;
    const short* Au = h3b;                       // users
    const short* Bi = h3b + (size_t)nu * 64;     // items
    bf16x8 a[4][2], b[4][2];
#pragma unroll
    for (int r = 0; r < 4; ++r)
#pragma unroll
        for (int kt = 0; kt < 2; ++kt) {
            a[r][kt] = *reinterpret_cast<const bf16x8*>(Au + (size_t)(row0 + r * 16 + lr) * 64 + kt * 32 + kg);
            b[r][kt] = *reinterpret_cast<const bf16x8*>(Bi + (size_t)(col0 + r * 16 + lr) * 64 + kt * 32 + kg);
        }
    f32x4 acc[4][4];
#pragma unroll
    for (int r = 0; r < 4; ++r)
#pragma unroll
        for (int c = 0; c < 4; ++c) {
            f32x4 z = {0.f, 0.f, 0.f, 0.f};
            z = __builtin_amdgcn_mfma_f32_16x16x32_bf16(a[r][0], b[c][0], z, 0, 0, 0);
            z = __builtin_amdgcn_mfma_f32_16x16x32_bf16(a[r][1], b[c][1], z, 0, 0, 0);
            acc[r][c] = z;
        }
    int rq = (lane >> 4) * 4;
#pragma unroll
    for (int r = 0; r < 4; ++r)
#pragma unroll
        for (int c = 0; c < 4; ++c)
#pragma unroll
            for (int q = 0; q < 4; ++q) {
                float v = acc[r][c][q];
                v = fminf(fmaxf(v, 1.f), 5.f);
                out[(size_t)(row0 + r * 16 + rq + q) * ni + col0 + c * 16 + lr] = v;
            }
}

// ---------------------------------------------------------------------------
extern "C" void kernel_launch(void* const* d_in, const int* in_sizes, int n_in,
                              void* d_out, int out_size, void* d_ws, size_t ws_size,
                              hipStream_t stream) {
    const int*   x   = (const int*)d_in[0];
    const int*   ei  = (const int*)d_in[1];
    const float* emb = (const float*)d_in[3];
    const float* W1  = (const float*)d_in[4];
    const float* b1  = (const float*)d_in[5];
    const float* W2  = (const float*)d_in[6];
    const float* b2  = (const float*)d_in[7];
    const float* Wl  = (const float*)d_in[8];
    const float* bl  = (const float*)d_in[9];
    float* out = (float*)d_out;

    const int n   = in_sizes[0];                 // 16384
    const int E   = in_sizes[1] / 2;             // 524288
    const int h1d = in_sizes[5];                 // 256
    const int d   = in_sizes[4] / h1d;           // 128
    const int embrows = in_sizes[3] / d;         // 8193
    const int nu  = n - (embrows - 1);           // 8192
    const int ni  = n - nu;                      // 8192

    const int* srcp = ei;
    const int* dstp = ei + E;

    char* w = (char*)d_ws;
    int*   counts  = (int*)(w + 0);                       // 64 KB
    int*   row_ptr = (int*)(w + (64 << 10));              // 64 KB
    int*   wp      = (int*)(w + (192 << 10));             // 64 KB
    float* dinv    = (float*)(w + (256 << 10));           // 64 KB
    int*   srcs    = (int*)(w + (320 << 10));             // 2 MB
    unsigned short* W1t = (unsigned short*)(w + 2621440);   // 64 KB
    unsigned short* W2t = (unsigned short*)(w + 2686976);   // 64 KB
    unsigned short* Wlt = (unsigned short*)(w + 2752512);   // 16 KB
    unsigned short* h0b  = (unsigned short*)(w + (4  << 20));  // 4 MB
    unsigned short* z1b  = (unsigned short*)(w + (8  << 20));  // 4 MB
    unsigned short* h1b  = (unsigned short*)(w + (12 << 20));  // 8 MB
    unsigned short* hw2b = (unsigned short*)(w + (20 << 20));  // 4 MB
    unsigned short* h2b  = (unsigned short*)(w + (24 << 20));  // 4 MB
    unsigned short* h3b  = (unsigned short*)(w + (28 << 20));  // 2 MB

    // zero atomic counters
    zero_kernel<<<(n + 255) / 256, 256, 0, stream>>>(counts, wp, n);

    // graph structure
    count_kernel<<<(E + 255) / 256, 256, 0, stream>>>(dstp, counts, E);
    scan_kernel<<<1, 256, 0, stream>>>(counts, row_ptr, dinv, n);
    scatter_kernel<<<(E + 255) / 256, 256, 0, stream>>>(srcp, dstp, row_ptr, wp, srcs, E);

    // h0 (bf16) + transposed bf16 weights, one dispatch
    prep_kernel<<<(n * 16 + 73728 + 255) / 256, 256, 0, stream>>>(
        x, emb, W1, W2, Wl, h0b, W1t, W2t, Wlt, nu, n);

    // conv1: z1 = A·h0 ; h1 = relu(z1 @ W1 + b1)
    agg_bf16_kernel<<<n, 64, 0, stream>>>(h0b, z1b, row_ptr, counts, srcs, dinv, nullptr, 0);
    {
        dim3 g(n / 64, h1d / 64);
        mfma_gemm_kernel<<<g, 256, 0, stream>>>(z1b, W1t, b1, h1b, n, h1d, d, 1);
    }

    // conv2: hw2 = h1 @ W2 ; h2 = relu(A·hw2 + b2)
    {
        dim3 g(n / 64, 128 / 64);
        mfma_gemm_kernel<<<g, 256, 0, stream>>>(h1b, W2t, nullptr, hw2b, n, 128, h1d, 0);
    }
    agg_bf16_kernel<<<n, 64, 0, stream>>>(hw2b, h2b, row_ptr, counts, srcs, dinv, b2, 1);

    // h3 = relu(h2 @ Wl + bl)
    {
        dim3 g(n / 64, 64 / 64);
        mfma_gemm_kernel<<<g, 256, 0, stream>>>(h2b, Wlt, bl, h3b, n, 64, 128, 1);
    }

    // result = clip(users @ items.T, 1, 5)
    {
        dim3 g(nu / 128, ni / 128);
        final_gemm_kernel<<<g, 256, 0, stream>>>((const short*)h3b, out, nu, ni);
    }
}